// Round 1
// baseline (840.075 us; speedup 1.0000x reference)
//
#include <hip/hip_runtime.h>

typedef __attribute__((ext_vector_type(4))) float floatx4;
typedef __bf16 bf16x8 __attribute__((ext_vector_type(8)));

#define ENC_STRIDE 520           // bf16 elems per enc row (512 + 8 pad; 1040B = 16B-aligned rows)
#define MEMT_STRIDE 40           // bf16 elems per mem-tile row (32 + 8 pad; 80B rows)
#define D2_STRIDE 257            // fp32 elems per d2 row (conflict-free column reads)
#define ENC_BYTES (32 * ENC_STRIDE * 2)    // 33280
#define MEMT_BYTES (256 * MEMT_STRIDE * 2) // 20480
#define SMEM_BYTES (ENC_BYTES + MEMT_BYTES)

// ---------------- kernel 0: exact fp32 query norms ----------------
__global__ __launch_bounds__(256) void k_e2(const float* __restrict__ enc,
                                            float* __restrict__ e2o) {
  int e = blockIdx.x;
  int t = threadIdx.x;
  int q = t >> 3, s = t & 7;
  const float4* p = reinterpret_cast<const float4*>(enc + ((size_t)e * 32 + q) * 512);
  float acc = 0.f;
#pragma unroll
  for (int i = 0; i < 16; ++i) {
    float4 v = p[s + 8 * i];
    acc += v.x * v.x + v.y * v.y + v.z * v.z + v.w * v.w;
  }
  acc += __shfl_xor(acc, 1);
  acc += __shfl_xor(acc, 2);
  acc += __shfl_xor(acc, 4);
  if (s == 0) e2o[e * 32 + q] = acc;
}

// ---------------- kernel 1: distances + per-block top-10 ----------------
__global__ __launch_bounds__(256, 2) void k_dist(const float* __restrict__ enc,
                                                 const float* __restrict__ mem,
                                                 const float* __restrict__ e2w,
                                                 float* __restrict__ topkw) {
  __shared__ __align__(16) char smem[SMEM_BYTES];
  __shared__ float m2s[256];
  unsigned short* encL = (unsigned short*)smem;                 // staging phase
  unsigned short* memL = (unsigned short*)(smem + ENC_BYTES);   // staging phase
  float* d2s = (float*)smem;                                    // epilogue (aliases encL, 32896B<=33280B)
  float* plist = (float*)(smem + ENC_BYTES);                    // epilogue (aliases memL, 11264B<=20480B)

  int e = blockIdx.x >> 4;
  int bm = blockIdx.x & 15;
  int t = threadIdx.x;
  const float* encE = enc + (size_t)e * 32 * 512;
  const float* memE = mem + ((size_t)e * 4096 + (size_t)bm * 256) * 512;

  m2s[t] = 0.f;

  // stage enc fp32 -> bf16 LDS (truncation; error ~0.1 in d2 of ~1024 -> negligible)
#pragma unroll
  for (int j = 0; j < 16; ++j) {
    int i = t + 256 * j;
    int q = i >> 7, c4 = i & 127;
    float4 v = *reinterpret_cast<const float4*>(encE + q * 512 + c4 * 4);
    uint2 pk;
    pk.x = (__float_as_uint(v.y) & 0xFFFF0000u) | (__float_as_uint(v.x) >> 16);
    pk.y = (__float_as_uint(v.w) & 0xFFFF0000u) | (__float_as_uint(v.z) >> 16);
    *reinterpret_cast<uint2*>(encL + q * ENC_STRIDE + c4 * 4) = pk;
  }
  __syncthreads();

  floatx4 acc[2][4] = {};

  int lane = t & 63;
  int w = t >> 6;
  int nidx = lane & 15;
  int quad = lane >> 4;

  for (int kt = 0; kt < 16; ++kt) {
    if (kt) __syncthreads();
    const float* src = memE + kt * 32;
#pragma unroll
    for (int j = 0; j < 8; ++j) {
      int i = t + 256 * j;
      int r = i >> 3, c4 = i & 7;
      float4 v = *reinterpret_cast<const float4*>(src + (size_t)r * 512 + c4 * 4);
      float sq = v.x * v.x + v.y * v.y + v.z * v.z + v.w * v.w;
      sq += __shfl_xor(sq, 1);
      sq += __shfl_xor(sq, 2);
      sq += __shfl_xor(sq, 4);
      if ((t & 7) == 0) m2s[r] += sq;   // unique r per 8-lane group; barriers order kt iters
      uint2 pk;
      pk.x = (__float_as_uint(v.y) & 0xFFFF0000u) | (__float_as_uint(v.x) >> 16);
      pk.y = (__float_as_uint(v.w) & 0xFFFF0000u) | (__float_as_uint(v.z) >> 16);
      *reinterpret_cast<uint2*>(memL + r * MEMT_STRIDE + c4 * 4) = pk;
    }
    __syncthreads();

    bf16x8 afrag[2], bfrag[4];
#pragma unroll
    for (int mt = 0; mt < 2; ++mt)
      afrag[mt] = *reinterpret_cast<const bf16x8*>(encL + (mt * 16 + nidx) * ENC_STRIDE + kt * 32 + quad * 8);
#pragma unroll
    for (int nt = 0; nt < 4; ++nt)
      bfrag[nt] = *reinterpret_cast<const bf16x8*>(memL + (w * 64 + nt * 16 + nidx) * MEMT_STRIDE + quad * 8);
#pragma unroll
    for (int mt = 0; mt < 2; ++mt)
#pragma unroll
      for (int nt = 0; nt < 4; ++nt)
        acc[mt][nt] = __builtin_amdgcn_mfma_f32_16x16x32_bf16(afrag[mt], bfrag[nt], acc[mt][nt], 0, 0, 0);
  }
  __syncthreads();  // all MFMA LDS reads done before aliasing smem as d2s/plist

  // epilogue: d2 = e2 + m2 - 2*dot  (C layout: row=q=quad*4+reg, col=r=lane&15)
#pragma unroll
  for (int mt = 0; mt < 2; ++mt) {
#pragma unroll
    for (int reg = 0; reg < 4; ++reg) {
      int q = mt * 16 + quad * 4 + reg;
      float e2v = e2w[e * 32 + q];
#pragma unroll
      for (int nt = 0; nt < 4; ++nt) {
        int r = w * 64 + nt * 16 + nidx;
        float d2 = e2v + m2s[r] - 2.0f * acc[mt][nt][reg];
        d2s[q * D2_STRIDE + r] = d2 > 0.f ? d2 : 0.f;
      }
    }
  }
  __syncthreads();

  // phase 1: 8 threads per query, each scans 32 values (stride-8 interleave)
  {
    int q = t >> 3, s = t & 7;
    float top[10];
#pragma unroll
    for (int i = 0; i < 10; ++i) top[i] = -1.f;
    for (int r0 = 0; r0 < 32; ++r0) {
      float v = d2s[q * D2_STRIDE + s + 8 * r0];
      if (v > top[9]) {
        top[9] = v;
#pragma unroll
        for (int i = 9; i > 0; --i)
          if (top[i] > top[i - 1]) { float tmp = top[i - 1]; top[i - 1] = top[i]; top[i] = tmp; }
      }
    }
#pragma unroll
    for (int i = 0; i < 10; ++i) plist[t * 11 + i] = top[i];
  }
  __syncthreads();

  // phase 2: merge 8 partial lists per query, write sorted top-10
  if (t < 32) {
    float top[10];
#pragma unroll
    for (int i = 0; i < 10; ++i) top[i] = -1.f;
    for (int s = 0; s < 8; ++s) {
#pragma unroll
      for (int j = 0; j < 10; ++j) {
        float v = plist[(t * 8 + s) * 11 + j];
        if (v > top[9]) {
          top[9] = v;
#pragma unroll
          for (int i = 9; i > 0; --i)
            if (top[i] > top[i - 1]) { float tmp = top[i - 1]; top[i - 1] = top[i]; top[i] = tmp; }
        }
      }
    }
    float* o = topkw + ((size_t)(e * 16 + bm) * 32 + t) * 10;
#pragma unroll
    for (int i = 0; i < 10; ++i) o[i] = top[i];
  }
}

// ---------------- kernel 2: merge block lists + sequential reward scan ----------------
__global__ __launch_bounds__(64) void k_reward(const float* __restrict__ topkw,
                                               float* __restrict__ out) {
  int e = blockIdx.x, t = threadIdx.x;
  __shared__ float knn[32][10];
  if (t < 32) {
    float top[10];
#pragma unroll
    for (int i = 0; i < 10; ++i) top[i] = -1.f;
    for (int bm = 0; bm < 16; ++bm) {
      const float* p = topkw + ((size_t)(e * 16 + bm) * 32 + t) * 10;
#pragma unroll
      for (int j = 0; j < 10; ++j) {
        float v = p[j];
        if (v > top[9]) {
          top[9] = v;
#pragma unroll
          for (int i = 9; i > 0; --i)
            if (top[i] > top[i - 1]) { float tmp = top[i - 1]; top[i - 1] = top[i]; top[i] = tmp; }
        }
      }
    }
#pragma unroll
    for (int i = 0; i < 10; ++i) knn[t][i] = top[i];
  }
  __syncthreads();
  if (t == 0) {
    float rm[10];
#pragma unroll
    for (int i = 0; i < 10; ++i) rm[i] = 0.f;
    for (int b = 0; b < 32; ++b) {
      float ssum = 0.f;
      float n = (float)(b + 1);
#pragma unroll
      for (int j = 0; j < 10; ++j) {
        float d = knn[b][j];
        rm[j] += (d - rm[j]) / n;
        float nd = d / rm[j] - 0.008f;
        nd = nd > 0.f ? nd : 0.f;
        ssum += 0.001f / (nd + 0.001f);
      }
      float sim = sqrtf(ssum) + 0.01f;
      out[e * 32 + b] = (sim > 8.0f) ? 0.f : 1.0f / sim;
    }
  }
}

extern "C" void kernel_launch(void* const* d_in, const int* in_sizes, int n_in,
                              void* d_out, int out_size, void* d_ws, size_t ws_size,
                              hipStream_t stream) {
  const float* enc = (const float*)d_in[0];   // (64, 32, 512) fp32
  const float* mem = (const float*)d_in[1];   // (64, 4096, 512) fp32
  float* out = (float*)d_out;                 // (64, 32) fp32
  float* e2w = (float*)d_ws;                  // 64*32 floats
  float* topkw = e2w + 64 * 32;               // 64*16*32*10 floats (~1.26 MB total ws)

  k_e2<<<64, 256, 0, stream>>>(enc, e2w);
  k_dist<<<1024, 256, 0, stream>>>(enc, mem, e2w, topkw);
  k_reward<<<64, 64, 0, stream>>>(topkw, out);
}

// Round 2
// 762.638 us; speedup vs baseline: 1.1015x; 1.1015x over previous
//
#include <hip/hip_runtime.h>

typedef __attribute__((ext_vector_type(4))) float floatx4;
typedef __bf16 bf16x8 __attribute__((ext_vector_type(8)));

#define ENC_STRIDE 520           // bf16 elems per enc row (512 + 8 pad; 1040B rows, 16B-aligned)
#define D2_STRIDE 260            // fp32: 260 mod 32 = 4 -> phase-1 reads (4q+s) 2-way max (free)
#define ENC_BYTES (32 * ENC_STRIDE * 2)   // 33280
#define D2_BYTES (32 * D2_STRIDE * 4)     // 33280 (aliases enc region exactly)
#define PLIST_SSTRIDE 353        // fp32 sublist-group stride: conflict-free phase-2, <=2-way phase-1
#define PLIST_BYTES (8 * PLIST_SSTRIDE * 4)  // 11296
#define SMEM_BYTES (ENC_BYTES + PLIST_BYTES) // 44576 -> 3 blocks/CU

// ---------------- kernel 0: exact fp32 query norms ----------------
__global__ __launch_bounds__(256) void k_e2(const float* __restrict__ enc,
                                            float* __restrict__ e2o) {
  int e = blockIdx.x;
  int t = threadIdx.x;
  int q = t >> 3, s = t & 7;
  const float4* p = reinterpret_cast<const float4*>(enc + ((size_t)e * 32 + q) * 512);
  float acc = 0.f;
#pragma unroll
  for (int i = 0; i < 16; ++i) {
    float4 v = p[s + 8 * i];
    acc += v.x * v.x + v.y * v.y + v.z * v.z + v.w * v.w;
  }
  acc += __shfl_xor(acc, 1);
  acc += __shfl_xor(acc, 2);
  acc += __shfl_xor(acc, 4);
  if (s == 0) e2o[e * 32 + q] = acc;
}

__device__ __forceinline__ uint2 pack_bf16x4(float4 v) {
  uint2 pk;
  pk.x = (__float_as_uint(v.y) & 0xFFFF0000u) | (__float_as_uint(v.x) >> 16);
  pk.y = (__float_as_uint(v.w) & 0xFFFF0000u) | (__float_as_uint(v.z) >> 16);
  return pk;
}

// ---------------- kernel 1: distances + per-block top-10 ----------------
// B-operand loaded global->register directly (MFMA B-frag is lane-contiguous in
// memory: lane reads 8 consecutive k floats of row n = nt*16 + (lane&15)).
// No barriers in the K-loop; register ping-pong prefetch of next k-tile.
__global__ __launch_bounds__(256, 3) void k_dist(const float* __restrict__ enc,
                                                 const float* __restrict__ mem,
                                                 const float* __restrict__ e2w,
                                                 float* __restrict__ topkw) {
  __shared__ __align__(16) char smem[SMEM_BYTES];
  unsigned short* encL = (unsigned short*)smem;            // K-loop phase
  float* d2s = (float*)smem;                               // epilogue (aliases encL)
  float* plist = (float*)(smem + ENC_BYTES);               // epilogue

  int e = blockIdx.x >> 4;
  int bm = blockIdx.x & 15;
  int t = threadIdx.x;
  const float* encE = enc + (size_t)e * 32 * 512;

  // stage enc fp32 -> bf16 LDS (coalesced float4)
#pragma unroll
  for (int j = 0; j < 16; ++j) {
    int i = t + 256 * j;
    int q = i >> 7, c4 = i & 127;
    float4 v = *reinterpret_cast<const float4*>(encE + q * 512 + c4 * 4);
    *reinterpret_cast<uint2*>(encL + q * ENC_STRIDE + c4 * 4) = pack_bf16x4(v);
  }
  __syncthreads();

  int lane = t & 63;
  int w = t >> 6;
  int nidx = lane & 15;
  int quad = lane >> 4;

  // per-lane row base pointers (quad picks the 8-float k-slice within each 32-k tile)
  const float* rp[4];
#pragma unroll
  for (int nt = 0; nt < 4; ++nt)
    rp[nt] = mem + ((size_t)e * 4096 + (size_t)bm * 256 + w * 64 + nt * 16 + nidx) * 512 + quad * 8;

  const unsigned short* aBase = encL + nidx * ENC_STRIDE + quad * 8;

  floatx4 acc[2][4] = {};
  float m2acc[4] = {0.f, 0.f, 0.f, 0.f};

  float4 bufA0[4], bufA1[4], bufB0[4], bufB1[4];
#pragma unroll
  for (int nt = 0; nt < 4; ++nt) {
    bufA0[nt] = *reinterpret_cast<const float4*>(rp[nt]);
    bufA1[nt] = *reinterpret_cast<const float4*>(rp[nt] + 4);
  }

  auto step = [&](float4* cur0, float4* cur1, float4* nxt0, float4* nxt1, int kt) {
    if (kt < 15) {
#pragma unroll
      for (int nt = 0; nt < 4; ++nt) {
        nxt0[nt] = *reinterpret_cast<const float4*>(rp[nt] + (kt + 1) * 32);
        nxt1[nt] = *reinterpret_cast<const float4*>(rp[nt] + (kt + 1) * 32 + 4);
      }
    }
    bf16x8 bfrag[4];
#pragma unroll
    for (int nt = 0; nt < 4; ++nt) {
      float4 v0 = cur0[nt], v1 = cur1[nt];
      m2acc[nt] += v0.x * v0.x + v0.y * v0.y + v0.z * v0.z + v0.w * v0.w
                 + v1.x * v1.x + v1.y * v1.y + v1.z * v1.z + v1.w * v1.w;
      uint2 p0 = pack_bf16x4(v0), p1 = pack_bf16x4(v1);
      uint4 pk = make_uint4(p0.x, p0.y, p1.x, p1.y);
      bfrag[nt] = *reinterpret_cast<bf16x8*>(&pk);
    }
    bf16x8 afrag[2];
#pragma unroll
    for (int mt = 0; mt < 2; ++mt)
      afrag[mt] = *reinterpret_cast<const bf16x8*>(aBase + mt * 16 * ENC_STRIDE + kt * 32);
#pragma unroll
    for (int mt = 0; mt < 2; ++mt)
#pragma unroll
      for (int nt = 0; nt < 4; ++nt)
        acc[mt][nt] = __builtin_amdgcn_mfma_f32_16x16x32_bf16(afrag[mt], bfrag[nt], acc[mt][nt], 0, 0, 0);
  };

#pragma unroll 1
  for (int kt2 = 0; kt2 < 8; ++kt2) {
    step(bufA0, bufA1, bufB0, bufB1, 2 * kt2);
    step(bufB0, bufB1, bufA0, bufA1, 2 * kt2 + 1);
  }

  // finish m2: sum across the 4 quads holding the same row
#pragma unroll
  for (int nt = 0; nt < 4; ++nt) {
    m2acc[nt] += __shfl_xor(m2acc[nt], 16);
    m2acc[nt] += __shfl_xor(m2acc[nt], 32);
  }

  __syncthreads();  // all A-frag ds_reads done before aliasing smem as d2s

  // epilogue: d2 = e2 + m2 - 2*dot  (C layout: row=q=quad*4+reg, col=r=lane&15)
#pragma unroll
  for (int mt = 0; mt < 2; ++mt) {
#pragma unroll
    for (int reg = 0; reg < 4; ++reg) {
      int q = mt * 16 + quad * 4 + reg;
      float e2v = e2w[e * 32 + q];
#pragma unroll
      for (int nt = 0; nt < 4; ++nt) {
        int r = w * 64 + nt * 16 + nidx;
        float d2 = e2v + m2acc[nt] - 2.0f * acc[mt][nt][reg];
        d2s[q * D2_STRIDE + r] = d2 > 0.f ? d2 : 0.f;
      }
    }
  }
  __syncthreads();

  // phase 1: 8 threads per query, each scans 32 values (stride-8 interleave)
  {
    int q = t >> 3, s = t & 7;
    float top[10];
#pragma unroll
    for (int i = 0; i < 10; ++i) top[i] = -1.f;
    for (int r0 = 0; r0 < 32; ++r0) {
      float v = d2s[q * D2_STRIDE + s + 8 * r0];
      if (v > top[9]) {
        top[9] = v;
#pragma unroll
        for (int i = 9; i > 0; --i)
          if (top[i] > top[i - 1]) { float tmp = top[i - 1]; top[i - 1] = top[i]; top[i] = tmp; }
      }
    }
#pragma unroll
    for (int i = 0; i < 10; ++i) plist[s * PLIST_SSTRIDE + q * 11 + i] = top[i];
  }
  __syncthreads();

  // phase 2: merge 8 partial lists per query, write sorted top-10
  if (t < 32) {
    float top[10];
#pragma unroll
    for (int i = 0; i < 10; ++i) top[i] = -1.f;
    for (int s = 0; s < 8; ++s) {
#pragma unroll
      for (int j = 0; j < 10; ++j) {
        float v = plist[s * PLIST_SSTRIDE + t * 11 + j];
        if (v > top[9]) {
          top[9] = v;
#pragma unroll
          for (int i = 9; i > 0; --i)
            if (top[i] > top[i - 1]) { float tmp = top[i - 1]; top[i - 1] = top[i]; top[i] = tmp; }
        }
      }
    }
    float* o = topkw + ((size_t)(e * 16 + bm) * 32 + t) * 10;
#pragma unroll
    for (int i = 0; i < 10; ++i) o[i] = top[i];
  }
}

// ---------------- kernel 2: merge block lists + sequential reward scan ----------------
__global__ __launch_bounds__(64) void k_reward(const float* __restrict__ topkw,
                                               float* __restrict__ out) {
  int e = blockIdx.x, t = threadIdx.x;
  __shared__ float knn[32][10];
  if (t < 32) {
    float top[10];
#pragma unroll
    for (int i = 0; i < 10; ++i) top[i] = -1.f;
    for (int bm = 0; bm < 16; ++bm) {
      const float* p = topkw + ((size_t)(e * 16 + bm) * 32 + t) * 10;
#pragma unroll
      for (int j = 0; j < 10; ++j) {
        float v = p[j];
        if (v > top[9]) {
          top[9] = v;
#pragma unroll
          for (int i = 9; i > 0; --i)
            if (top[i] > top[i - 1]) { float tmp = top[i - 1]; top[i - 1] = top[i]; top[i] = tmp; }
        }
      }
    }
#pragma unroll
    for (int i = 0; i < 10; ++i) knn[t][i] = top[i];
  }
  __syncthreads();
  if (t == 0) {
    float rm[10];
#pragma unroll
    for (int i = 0; i < 10; ++i) rm[i] = 0.f;
    for (int b = 0; b < 32; ++b) {
      float ssum = 0.f;
      float n = (float)(b + 1);
#pragma unroll
      for (int j = 0; j < 10; ++j) {
        float d = knn[b][j];
        rm[j] += (d - rm[j]) / n;
        float nd = d / rm[j] - 0.008f;
        nd = nd > 0.f ? nd : 0.f;
        ssum += 0.001f / (nd + 0.001f);
      }
      float sim = sqrtf(ssum) + 0.01f;
      out[e * 32 + b] = (sim > 8.0f) ? 0.f : 1.0f / sim;
    }
  }
}

extern "C" void kernel_launch(void* const* d_in, const int* in_sizes, int n_in,
                              void* d_out, int out_size, void* d_ws, size_t ws_size,
                              hipStream_t stream) {
  const float* enc = (const float*)d_in[0];   // (64, 32, 512) fp32
  const float* mem = (const float*)d_in[1];   // (64, 4096, 512) fp32
  float* out = (float*)d_out;                 // (64, 32) fp32
  float* e2w = (float*)d_ws;                  // 64*32 floats
  float* topkw = e2w + 64 * 32;               // 64*16*32*10 floats

  k_e2<<<64, 256, 0, stream>>>(enc, e2w);
  k_dist<<<1024, 256, 0, stream>>>(enc, mem, e2w, topkw);
  k_reward<<<64, 64, 0, stream>>>(topkw, out);
}